// Round 1
// baseline (669.331 us; speedup 1.0000x reference)
//
#include <hip/hip_runtime.h>

#define D 128
#define NUM_GRAPHS 4096

typedef float v4f __attribute__((ext_vector_type(4)));

#define RFL(x) __builtin_amdgcn_readfirstlane(x)

__device__ __forceinline__ float dot4(v4f h, v4f w) {
    return h.x * w.x + h.y * w.y + h.z * w.z + h.w * w.w;
}

// Flush per-lane accumulator to global. Graph ids are wave-uniform scalars
// (cg_e for even rows / half 0, cg_o for odd rows / half 1).
__device__ __forceinline__ void flushv(float* __restrict__ S, float* __restrict__ Z,
                                       int cg_e, int cg_o, int half, int colbase,
                                       bool zlane, v4f& acc, float& zacc) {
    const int cur_g = half ? cg_o : cg_e;
    float* p = &S[(size_t)cur_g * D + colbase];
    atomicAdd(p + 0, acc.x);
    atomicAdd(p + 1, acc.y);
    atomicAdd(p + 2, acc.z);
    atomicAdd(p + 3, acc.w);
    if (zlane) atomicAdd(&Z[cur_g], zacc);
    acc = (v4f)(0.f);
    zacc = 0.f;
}

// Layout: lane l loads float4 -> one 1KB wave-load covers TWO rows.
//   lanes 0..31  = row v   (cols 4*(l&31)..+3)
//   lanes 32..63 = row v+1
// Batch ids are loaded via wave-uniform (scalar) loads: v is uniform, batch is
// sorted, so quad-cleanliness is a single scalar compare (a0 == b3). Hot loop
// VMEM = exactly 4 global_load_dwordx4 (the H quad prefetch); vmcnt drain at
// the pipeline rotation waits on nothing else.
__global__ __launch_bounds__(256, 8) void attn_agg_accum(
    const float* __restrict__ H, const int* __restrict__ batch,
    const float* __restrict__ w, const float* __restrict__ b,
    float* __restrict__ S /* [NUM_GRAPHS*D] = d_out */,
    float* __restrict__ Z /* [NUM_GRAPHS] */,
    int V)
{
    const int lane    = threadIdx.x & 63;
    const int half    = lane >> 5;           // 0: even row of pair, 1: odd row
    const int colbase = (lane & 31) << 2;
    const bool zlane  = (lane & 31) == 0;

    int wid = blockIdx.x * (blockDim.x >> 6) + (threadIdx.x >> 6);
    wid = RFL(wid);                          // pin uniform -> scalar addressing below
    const int total_waves = gridDim.x * (blockDim.x >> 6);
    // rows per wave, multiple of 8 so every chunk is whole quads (V=1e6 = 8*125000)
    const int rpw = ((V + total_waves * 8 - 1) / (total_waves * 8)) * 8;

    const int row0 = wid * rpw;
    if (row0 >= V) return;
    int row1 = row0 + rpw;
    if (row1 > V) row1 = V;

    const v4f w4     = ((const v4f*)w)[lane & 31];
    const float bias = b[0];
    const v4f* __restrict__ Hp = (const v4f*)H;   // row r = Hp[r*32 + (lane&31)] per half

    v4f acc    = (v4f)(0.f);
    float zacc = 0.f;

    // current graph of even/odd rows, wave-uniform scalars
    const int2 cgi = *(const int2*)(batch + row0);   // uniform addr, 8B aligned
    int cg_e = RFL(cgi.x);
    int cg_o = RFL(cgi.y);

    int v = row0;
    v4f h0, h1, h2, h3;
    if (v + 8 <= row1) {
        h0 = __builtin_nontemporal_load(&Hp[(size_t)(v + 0) * 32 + lane]);
        h1 = __builtin_nontemporal_load(&Hp[(size_t)(v + 2) * 32 + lane]);
        h2 = __builtin_nontemporal_load(&Hp[(size_t)(v + 4) * 32 + lane]);
        h3 = __builtin_nontemporal_load(&Hp[(size_t)(v + 6) * 32 + lane]);
    }

    while (v + 8 <= row1) {
        const int nv = v + 8;

        // graph ids for CURRENT quad: uniform 16B loads (constant cache),
        // issued here so their latency hides under the dot+shuffle chain
        const int4 t0 = *(const int4*)(batch + v);       // rows v..v+3
        const int4 t1 = *(const int4*)(batch + v + 4);   // rows v+4..v+7

        v4f n0 = h0, n1 = h1, n2 = h2, n3 = h3;
        if (nv + 8 <= row1) {                    // prefetch next quad (4KB/wave in flight)
            n0 = __builtin_nontemporal_load(&Hp[(size_t)(nv + 0) * 32 + lane]);
            n1 = __builtin_nontemporal_load(&Hp[(size_t)(nv + 2) * 32 + lane]);
            n2 = __builtin_nontemporal_load(&Hp[(size_t)(nv + 4) * 32 + lane]);
            n3 = __builtin_nontemporal_load(&Hp[(size_t)(nv + 6) * 32 + lane]);
        }

        float d0 = dot4(h0, w4);
        float d1 = dot4(h1, w4);
        float d2 = dot4(h2, w4);
        float d3 = dot4(h3, w4);
        #pragma unroll
        for (int off = 16; off > 0; off >>= 1) {  // stays within each half-wave
            d0 += __shfl_xor(d0, off, 64);
            d1 += __shfl_xor(d1, off, 64);
            d2 += __shfl_xor(d2, off, 64);
            d3 += __shfl_xor(d3, off, 64);
        }

        const float l0 = __expf(d0 + bias);
        const float l1 = __expf(d1 + bias);
        const float l2 = __expf(d2 + bias);
        const float l3 = __expf(d3 + bias);

        const int a0 = RFL(t0.x), a1 = RFL(t0.y), a2 = RFL(t0.z), a3 = RFL(t0.w);
        const int b0 = RFL(t1.x), b1 = RFL(t1.y), b2 = RFL(t1.z), b3 = RFL(t1.w);

        // batch is sorted: whole quad in one graph <=> a0 == b3 (scalar branch)
        if (__builtin_expect(a0 == b3 && a0 == cg_e && a0 == cg_o, 1)) {
            acc += h0 * l0 + h1 * l1 + h2 * l2 + h3 * l3;
            zacc += l0 + l1 + l2 + l3;
        } else {                                  // boundary in quad (~1/30 iters)
            if (a0 != cg_e || a1 != cg_o) { flushv(S, Z, cg_e, cg_o, half, colbase, zlane, acc, zacc); cg_e = a0; cg_o = a1; }
            acc += h0 * l0; zacc += l0;
            if (a2 != cg_e || a3 != cg_o) { flushv(S, Z, cg_e, cg_o, half, colbase, zlane, acc, zacc); cg_e = a2; cg_o = a3; }
            acc += h1 * l1; zacc += l1;
            if (b0 != cg_e || b1 != cg_o) { flushv(S, Z, cg_e, cg_o, half, colbase, zlane, acc, zacc); cg_e = b0; cg_o = b1; }
            acc += h2 * l2; zacc += l2;
            if (b2 != cg_e || b3 != cg_o) { flushv(S, Z, cg_e, cg_o, half, colbase, zlane, acc, zacc); cg_e = b2; cg_o = b3; }
            acc += h3 * l3; zacc += l3;
        }

        h0 = n0; h1 = n1; h2 = n2; h3 = n3;
        v = nv;
    }

    // pair remainder (chunks are quad-multiples, but keep for safety)
    for (; v + 2 <= row1; v += 2) {
        const int2 t = *(const int2*)(batch + v);    // uniform
        v4f h = __builtin_nontemporal_load(&Hp[(size_t)v * 32 + lane]);
        float d = dot4(h, w4);
        #pragma unroll
        for (int off = 16; off > 0; off >>= 1)
            d += __shfl_xor(d, off, 64);
        const float l = __expf(d + bias);
        const int ge = RFL(t.x), go = RFL(t.y);
        if (ge != cg_e || go != cg_o) { flushv(S, Z, cg_e, cg_o, half, colbase, zlane, acc, zacc); cg_e = ge; cg_o = go; }
        acc += h * l; zacc += l;
    }

    flushv(S, Z, cg_e, cg_o, half, colbase, zlane, acc, zacc);
}

__global__ __launch_bounds__(256) void attn_agg_norm(
    float4* __restrict__ out, const float* __restrict__ Z, int n4)
{
    const int i = blockIdx.x * blockDim.x + threadIdx.x;
    if (i < n4) {
        const int g = i >> 5;            // D == 128 -> 32 float4 per row
        const float z = Z[g];
        float4 o = out[i];
        o.x /= z; o.y /= z; o.z /= z; o.w /= z;
        out[i] = o;
    }
}

extern "C" void kernel_launch(void* const* d_in, const int* in_sizes, int n_in,
                              void* d_out, int out_size, void* d_ws, size_t ws_size,
                              hipStream_t stream) {
    const float* H     = (const float*)d_in[0];
    const int*   batch = (const int*)  d_in[1];
    const float* w     = (const float*)d_in[2];
    const float* b     = (const float*)d_in[3];
    float* out = (float*)d_out;          // [NUM_GRAPHS, D] accumulator + result
    float* Z   = (float*)d_ws;           // [NUM_GRAPHS]

    const int V = in_sizes[0] / D;       // 1,000,000

    hipMemsetAsync(out, 0, (size_t)out_size * sizeof(float), stream);
    hipMemsetAsync(Z,   0, NUM_GRAPHS * sizeof(float), stream);

    // 2048 blocks x 256 threads = 8192 waves; each wave streams 128 rows (16 quads)
    attn_agg_accum<<<2048, 256, 0, stream>>>(H, batch, w, b, out, Z, V);

    const int n4 = NUM_GRAPHS * D / 4;
    attn_agg_norm<<<(n4 + 255) / 256, 256, 0, stream>>>((float4*)out, Z, n4);
}